// Round 9
// baseline (372.968 us; speedup 1.0000x reference)
//
#include <hip/hip_runtime.h>

// Problem constants (fixed by reference)
#define N_NODES 2048
#define EMBED   32
#define B_BATCH 16
#define INP     32
#define OUTC    32
#define NCOL    512
#define CHEB_K  3
#define NB      512   // persistent grid: 2 blocks/CU on 256 CUs

// R9: fused persistent kernel, CACHED stores + correct cheap barrier:
//  release-fence(once)/relaxed-arrive/relaxed-spin/acquire-fence(once).
//  R7's 90us/barrier = acquire-per-poll (L2 inv storm). R8's 200us =
//  write-through amplification (WRITE 69.8MB vs 26 logical) + 1-deep MLP.
//  Atomics replace the Vp-chunk reductions: 6 barriers -> 4.

__device__ __forceinline__ void grid_sync(unsigned* bar, unsigned target) {
    __syncthreads();   // all block stores issued, vmcnt drained
    if (threadIdx.x == 0) {
        __builtin_amdgcn_fence(__ATOMIC_RELEASE, "agent");   // wb own-XCD L2, once
        __hip_atomic_fetch_add(&bar[0], 1u, __ATOMIC_RELAXED, __HIP_MEMORY_SCOPE_AGENT);
        while (__hip_atomic_load(&bar[0], __ATOMIC_RELAXED, __HIP_MEMORY_SCOPE_AGENT) < target)
            __builtin_amdgcn_s_sleep(8);
        __builtin_amdgcn_fence(__ATOMIC_ACQUIRE, "agent");   // inv own L1/L2, once
    }
    __syncthreads();
}

__global__ __launch_bounds__(256, 2) void k_fused(
    const float* __restrict__ XT, const float* __restrict__ adj,
    const float* __restrict__ gammap, const float* __restrict__ W,
    const float* __restrict__ bp, const float* __restrict__ p,
    const float* __restrict__ pb, const float* __restrict__ drop,
    float* __restrict__ Ehat, float* __restrict__ Psum, float* __restrict__ inv,
    float* __restrict__ V1, float* __restrict__ V2, float* __restrict__ M,
    float* __restrict__ qpart, unsigned* __restrict__ bar,
    float* __restrict__ out)
{
    __shared__ float sm[5760];        // 23040 B, phase-aliased
    const int tid = threadIdx.x;
    const int bid = blockIdx.x;

    // ---------------- Phase 1: gram tiles + zero the atomic targets ---------
    {
        const int z = bid * 256 + tid;                 // 0..131071
        if (z < 65536) { V1[z] = 0.f; V2[z] = 0.f; }
        if (z < 49152) M[z] = 0.f;
        if (bid == 0) { out[tid] = 0.f; out[256 + tid] = 0.f; }

        float* ai  = sm;              // [64][36]
        float* ajT = sm + 2304;       // [32][68]
        float* nI  = sm + 4480;       // [64]
        float* nJ  = sm + 4544;       // [64]
        float* rm  = sm + 4608;       // [64][17]
        const float gamma = gammap[0];
        for (int tile = bid; tile < 1024; tile += NB) {
            const int j0 = (tile & 31) * 64;
            const int i0 = (tile >> 5) * 64;
            __syncthreads();
#pragma unroll
            for (int r = 0; r < 8; r++) {
                const int idx = r * 256 + tid;       // 0..2047
                ai[(idx >> 5) * 36 + (idx & 31)]  = adj[(size_t)(i0 + (idx >> 5)) * EMBED + (idx & 31)];
                ajT[(idx & 31) * 68 + (idx >> 5)] = adj[(size_t)(j0 + (idx >> 5)) * EMBED + (idx & 31)];
            }
            __syncthreads();
            if (tid < 64) {
                float s = 0.f;
#pragma unroll
                for (int k = 0; k < 32; k++) { const float v = ai[tid * 36 + k]; s += v * v; }
                nI[tid] = s;
            } else if (tid < 128) {
                const int col = tid - 64;
                float s = 0.f;
#pragma unroll
                for (int k = 0; k < 32; k++) { const float v = ajT[k * 68 + col]; s += v * v; }
                nJ[col] = s;
            }
            __syncthreads();
            const int ti = tid >> 4, tj = tid & 15;
            float acc[4][4] = {};
#pragma unroll
            for (int k4 = 0; k4 < 8; k4++) {
                float4 a4[4], b4[4];
#pragma unroll
                for (int r = 0; r < 4; r++) a4[r] = *(const float4*)&ai[(ti * 4 + r) * 36 + k4 * 4];
#pragma unroll
                for (int kk = 0; kk < 4; kk++) b4[kk] = *(const float4*)&ajT[(k4 * 4 + kk) * 68 + tj * 4];
#pragma unroll
                for (int r = 0; r < 4; r++) {
                    acc[r][0] += a4[r].x * b4[0].x + a4[r].y * b4[1].x + a4[r].z * b4[2].x + a4[r].w * b4[3].x;
                    acc[r][1] += a4[r].x * b4[0].y + a4[r].y * b4[1].y + a4[r].z * b4[2].y + a4[r].w * b4[3].y;
                    acc[r][2] += a4[r].x * b4[0].z + a4[r].y * b4[1].z + a4[r].z * b4[2].z + a4[r].w * b4[3].z;
                    acc[r][3] += a4[r].x * b4[0].w + a4[r].y * b4[1].w + a4[r].z * b4[2].w + a4[r].w * b4[3].w;
                }
            }
#pragma unroll
            for (int r = 0; r < 4; r++) {
                const int i = i0 + ti * 4 + r;
                const float ni = nI[ti * 4 + r];
                float e[4];
#pragma unroll
                for (int c = 0; c < 4; c++) {
                    const float dist = ni + nJ[tj * 4 + c] - 2.f * acc[r][c];
                    e[c] = __expf(__expf(-gamma * dist));
                }
                rm[(ti * 4 + r) * 17 + tj] = e[0] + e[1] + e[2] + e[3];
                const float4 dr = *(const float4*)&drop[(size_t)i * N_NODES + j0 + tj * 4];
                *(float4*)&Ehat[(size_t)i * N_NODES + j0 + tj * 4] =
                    make_float4(e[0] * dr.x, e[1] * dr.y, e[2] * dr.z, e[3] * dr.w);
            }
            __syncthreads();
            if (tid < 64) {
                float s = 0.f;
#pragma unroll
                for (int t = 0; t < 16; t++) s += rm[tid * 17 + t];
                Psum[(size_t)(tile & 31) * N_NODES + i0 + tid] = s;
            }
        }
    }
    grid_sync(bar, NB * 1);

    // ---------------- Phase 2: inv + qpart + V1 += A^T U' -------------------
    if (bid < 256) {
        float* invL = sm;            // 128
        float* red  = sm + 128;      // 256
        float* Us   = sm + 384;      // 4096 (128 rows x 32 d)
        const int nt = bid >> 4;     // n-tile (128 cols)
        const int mc = bid & 15;     // m-chunk (128 rows)
        const int m0 = mc * 128;
        {
            const int row = tid & 127, h = tid >> 7;
            float s = 0.f;
#pragma unroll
            for (int t = 0; t < 16; t++)
                s += Psum[(size_t)(h * 16 + t) * N_NODES + m0 + row];
            red[tid] = s;
        }
        __syncthreads();
        if (tid < 128) {
            const float iv = 1.0f / (red[tid] + red[128 + tid]);
            invL[tid] = iv;
            if (nt == 0) inv[m0 + tid] = iv;
        }
        __syncthreads();
        float qs = 0.f;
#pragma unroll
        for (int r = 0; r < 16; r++) {
            const int idx = r * 256 + tid;           // 0..4095
            const int row = idx >> 5;
            const float u = p[m0 + row] * adj[(size_t)m0 * EMBED + idx];
            Us[idx] = invL[row] * u;
            qs += u;
        }
        __syncthreads();
        if (nt == 0) {
            red[tid] = qs;
            __syncthreads();
            if (tid < 32) {
                float t = 0.f;
#pragma unroll
                for (int gg = 0; gg < 8; gg++) t += red[gg * 32 + tid];
                qpart[mc * EMBED + tid] = t;
            }
            __syncthreads();
        }
        const int n  = nt * 128 + (tid & 127);
        const int dh = (tid >> 7) * 16;
        const float* Ep = &Ehat[(size_t)m0 * N_NODES + n];
        float4 a0 = {}, a1 = {}, a2 = {}, a3 = {};
        for (int mm = 0; mm < 128; mm += 4) {
            const float e0 = Ep[(size_t)(mm + 0) * N_NODES];
            const float e1 = Ep[(size_t)(mm + 1) * N_NODES];
            const float e2 = Ep[(size_t)(mm + 2) * N_NODES];
            const float e3 = Ep[(size_t)(mm + 3) * N_NODES];
#pragma unroll
            for (int j = 0; j < 4; j++) {
                const float e = (j == 0) ? e0 : (j == 1) ? e1 : (j == 2) ? e2 : e3;
                const float4* u4 = (const float4*)&Us[(mm + j) * 32 + dh];
                const float4 u0 = u4[0], u1 = u4[1], u2 = u4[2], u3 = u4[3];
                a0.x += e * u0.x; a0.y += e * u0.y; a0.z += e * u0.z; a0.w += e * u0.w;
                a1.x += e * u1.x; a1.y += e * u1.y; a1.z += e * u1.z; a1.w += e * u1.w;
                a2.x += e * u2.x; a2.y += e * u2.y; a2.z += e * u2.z; a2.w += e * u2.w;
                a3.x += e * u3.x; a3.y += e * u3.y; a3.z += e * u3.z; a3.w += e * u3.w;
            }
        }
        float* o = &V1[(size_t)n * EMBED + dh];
        atomicAdd(&o[0],  a0.x); atomicAdd(&o[1],  a0.y); atomicAdd(&o[2],  a0.z); atomicAdd(&o[3],  a0.w);
        atomicAdd(&o[4],  a1.x); atomicAdd(&o[5],  a1.y); atomicAdd(&o[6],  a1.z); atomicAdd(&o[7],  a1.w);
        atomicAdd(&o[8],  a2.x); atomicAdd(&o[9],  a2.y); atomicAdd(&o[10], a2.z); atomicAdd(&o[11], a2.w);
        atomicAdd(&o[12], a3.x); atomicAdd(&o[13], a3.y); atomicAdd(&o[14], a3.z); atomicAdd(&o[15], a3.w);
    }
    grid_sync(bar, NB * 2);

    // ---------------- Phase 3: V2 += A^T (inv o V1) -------------------------
    if (bid < 256) {
        float* Us = sm;              // 4096
        const int nt = bid >> 4;
        const int mc = bid & 15;
        const int m0 = mc * 128;
#pragma unroll
        for (int r = 0; r < 16; r++) {
            const int idx = r * 256 + tid;
            Us[idx] = inv[m0 + (idx >> 5)] * V1[(size_t)m0 * EMBED + idx];
        }
        __syncthreads();
        const int n  = nt * 128 + (tid & 127);
        const int dh = (tid >> 7) * 16;
        const float* Ep = &Ehat[(size_t)m0 * N_NODES + n];
        float4 a0 = {}, a1 = {}, a2 = {}, a3 = {};
        for (int mm = 0; mm < 128; mm += 4) {
            const float e0 = Ep[(size_t)(mm + 0) * N_NODES];
            const float e1 = Ep[(size_t)(mm + 1) * N_NODES];
            const float e2 = Ep[(size_t)(mm + 2) * N_NODES];
            const float e3 = Ep[(size_t)(mm + 3) * N_NODES];
#pragma unroll
            for (int j = 0; j < 4; j++) {
                const float e = (j == 0) ? e0 : (j == 1) ? e1 : (j == 2) ? e2 : e3;
                const float4* u4 = (const float4*)&Us[(mm + j) * 32 + dh];
                const float4 u0 = u4[0], u1 = u4[1], u2 = u4[2], u3 = u4[3];
                a0.x += e * u0.x; a0.y += e * u0.y; a0.z += e * u0.z; a0.w += e * u0.w;
                a1.x += e * u1.x; a1.y += e * u1.y; a1.z += e * u1.z; a1.w += e * u1.w;
                a2.x += e * u2.x; a2.y += e * u2.y; a2.z += e * u2.z; a2.w += e * u2.w;
                a3.x += e * u3.x; a3.y += e * u3.y; a3.z += e * u3.z; a3.w += e * u3.w;
            }
        }
        float* o = &V2[(size_t)n * EMBED + dh];
        atomicAdd(&o[0],  a0.x); atomicAdd(&o[1],  a0.y); atomicAdd(&o[2],  a0.z); atomicAdd(&o[3],  a0.w);
        atomicAdd(&o[4],  a1.x); atomicAdd(&o[5],  a1.y); atomicAdd(&o[6],  a1.z); atomicAdd(&o[7],  a1.w);
        atomicAdd(&o[8],  a2.x); atomicAdd(&o[9],  a2.y); atomicAdd(&o[10], a2.z); atomicAdd(&o[11], a2.w);
        atomicAdd(&o[12], a3.x); atomicAdd(&o[13], a3.y); atomicAdd(&o[14], a3.z); atomicAdd(&o[15], a3.w);
    }
    grid_sync(bar, NB * 3);

    // ---------------- Phase 4: M += Vk^T X' ---------------------------------
    if (bid < 128) {
        float* xs = sm;              // [32][65] = 2080
        float* vs = sm + 2080;       // [3][1024]
        const int c0 = (bid >> 3) * 32;
        const int nc = bid & 7;      // 256-row n-chunk
        const int d  = tid >> 3;
        const int cg = (tid & 7) * 4;
        float acc[3][4] = {};
#pragma unroll
        for (int s = 0; s < 4; s++) {
            const int n0 = nc * 256 + s * 64;
            __syncthreads();
#pragma unroll
            for (int r = 0; r < 8; r++) {
                const int idx = r * 256 + tid;       // 0..2047
                xs[(idx >> 6) * 65 + (idx & 63)] = XT[(size_t)(c0 + (idx >> 6)) * N_NODES + n0 + (idx & 63)];
            }
#pragma unroll
            for (int h = 0; h < 2; h++) {
                __syncthreads();
#pragma unroll
                for (int r = 0; r < 4; r++) {
                    const int idx = r * 256 + tid;   // 0..1023
                    const int row = n0 + h * 32;
                    vs[idx]        = p[row + (idx >> 5)] * adj[(size_t)row * EMBED + idx];
                    vs[1024 + idx] = V1[(size_t)row * EMBED + idx];
                    vs[2048 + idx] = V2[(size_t)row * EMBED + idx];
                }
                __syncthreads();
#pragma unroll 4
                for (int nn = 0; nn < 32; nn++) {
                    const float v0 = vs[nn * 32 + d];
                    const float v1 = vs[1024 + nn * 32 + d];
                    const float v2 = vs[2048 + nn * 32 + d];
#pragma unroll
                    for (int cc = 0; cc < 4; cc++) {
                        const float xv = xs[(cg + cc) * 65 + h * 32 + nn];
                        acc[0][cc] += xv * v0;
                        acc[1][cc] += xv * v1;
                        acc[2][cc] += xv * v2;
                    }
                }
            }
        }
#pragma unroll
        for (int k = 0; k < 3; k++)
#pragma unroll
            for (int cc = 0; cc < 4; cc++)
                atomicAdd(&M[(size_t)(k * EMBED + d) * NCOL + c0 + cg + cc], acc[k][cc]);
    }
    grid_sync(bar, NB * 4);

    // ---------------- Phase 5: split-d epilogue -----------------------------
    if (bid < 32) {
        float* wL = sm;              // 3072
        float* mL = sm + 3072;       // 1536
        float* qL = sm + 4608;       // 32
        const int d = bid;
#pragma unroll
        for (int r = 0; r < 12; r++) {
            const int idx = r * 256 + tid;           // 0..3071
            const int k = idx >> 10;
            wL[idx] = W[((size_t)(d * 3 + k) << 10) + (idx & 1023)];
        }
#pragma unroll
        for (int r = 0; r < 6; r++) {
            const int e = r * 256 + tid;             // 0..1535
            const int k = e >> 9;
            const int c = e & 511;
            mL[k * 512 + c] = M[(size_t)(k * EMBED + d) * NCOL + c];
        }
        if (d == 0 && tid < 32) {
            float s = 0.f;
#pragma unroll
            for (int mc = 0; mc < 16; mc++) s += qpart[mc * EMBED + tid];
            qL[tid] = s;
        }
        __syncthreads();
#pragma unroll
        for (int r = 0; r < 2; r++) {
            const int pair = r * 256 + tid;          // 0..511 = b*32+o
            const int b = pair >> 5;
            const int o = pair & 31;
            float acc = 0.f;
#pragma unroll
            for (int i = 0; i < 32; i++) {
                const float m0 = mL[b * 32 + i];
                const float m1 = mL[512 + b * 32 + i];
                const float m2 = mL[1024 + b * 32 + i];
                const float w0 = wL[i * 32 + o];
                const float w1 = wL[1024 + i * 32 + o];
                const float w2 = wL[2048 + i * 32 + o];
                acc += m0 * (w0 - w2) + m1 * w1 + 2.f * m2 * w2;
            }
            if (d == 0) {
                float bias = pb[0];
#pragma unroll
                for (int dd = 0; dd < 32; dd++) bias += qL[dd] * bp[dd * OUTC + o];
                acc += bias;
            }
            atomicAdd(&out[pair], acc);
        }
    }
}

// ---------------------------------------------------------------------------
extern "C" void kernel_launch(void* const* d_in, const int* in_sizes, int n_in,
                              void* d_out, int out_size, void* d_ws, size_t ws_size,
                              hipStream_t stream)
{
    const float* x     = (const float*)d_in[0];
    const float* adj   = (const float*)d_in[1];
    const float* gamma = (const float*)d_in[2];
    const float* Wp    = (const float*)d_in[3];
    const float* bp    = (const float*)d_in[4];
    const float* pw    = (const float*)d_in[5];
    const float* pb    = (const float*)d_in[6];
    const float* drop  = (const float*)d_in[7];
    float* out = (float*)d_out;

    float* ws = (float*)d_ws;
    unsigned* bar = (unsigned*)ws;                            // 128 B
    float* Ehat  = ws + 32;                                   // 16 MB
    float* Psum  = Ehat + (size_t)N_NODES * N_NODES;          // 256 KB
    float* inv   = Psum + (size_t)32 * N_NODES;               // 8 KB
    float* V1    = inv  + N_NODES;                            // 256 KB
    float* V2    = V1   + (size_t)N_NODES * EMBED;            // 256 KB
    float* M     = V2   + (size_t)N_NODES * EMBED;            // 192 KB
    float* qpart = M    + (size_t)CHEB_K * EMBED * NCOL;      // 2 KB

    hipMemsetAsync(bar, 0, 128, stream);
    k_fused<<<NB, 256, 0, stream>>>(x, adj, gamma, Wp, bp, pw, pb, drop,
                                    Ehat, Psum, inv, V1, V2, M,
                                    qpart, bar, out);
}

// Round 10
// 137.528 us; speedup vs baseline: 2.7119x; 2.7119x over previous
//
#include <hip/hip_runtime.h>

// Problem constants (fixed by reference)
#define N_NODES 2048
#define EMBED   32
#define B_BATCH 16
#define INP     32
#define OUTC    32
#define NCOL    512
#define CHEB_K  3

// R10: back to the R5 multi-dispatch structure (persistent-kernel fusion is
// a dead end on gfx950: software grid barriers cost 90us w/ per-poll acquire,
// ~30us+ w/ per-block fences, and write-through stores amplify HBM writes
// 2.6-4x; kernel boundaries are cheaper). Fixes vs R5:
//  - k_Mred: coalesced Mp chunk-reduction (was a 196KB-stride 32-chunk loop
//    inside 32-block k_final = 51us of cross-XCD latency).
//  - k_final: 128 blocks, reads tiny pre-reduced M + L2-resident W.
//  - k_v: explicit 4-deep MLP on the strided Ehat loads (R8-verified pattern).

// ---------------------------------------------------------------------------
// k_gram: 64x64 tiles. Ehat[i][j] = exp(exp(-gamma*dist(i,j))) * drop[i][j],
// Psum[jt][i] = sum_{j in tile jt} exp(exp(-gamma*dist)).  grid (32 jt, 32 it).
// ---------------------------------------------------------------------------
__global__ __launch_bounds__(256) void k_gram(
    const float* __restrict__ adj, const float* __restrict__ gammap,
    const float* __restrict__ drop,
    float* __restrict__ Ehat, float* __restrict__ Psum)
{
    __shared__ float ai[64][36];     // [row][k]
    __shared__ float ajT[32][68];    // [k][col]
    __shared__ float nI[64], nJ[64];
    __shared__ float rm[64][17];
    const int tid = threadIdx.x;
    const int j0 = blockIdx.x * 64;
    const int i0 = blockIdx.y * 64;
    const float gamma = gammap[0];

#pragma unroll
    for (int r = 0; r < 8; r++) {
        const int idx = r * 256 + tid;           // 0..2047
        ai[idx >> 5][idx & 31]  = adj[(size_t)(i0 + (idx >> 5)) * EMBED + (idx & 31)];
        ajT[idx & 31][idx >> 5] = adj[(size_t)(j0 + (idx >> 5)) * EMBED + (idx & 31)];
    }
    __syncthreads();
    if (tid < 64) {
        float s = 0.f;
#pragma unroll
        for (int k = 0; k < 32; k++) { const float v = ai[tid][k]; s += v * v; }
        nI[tid] = s;
    } else if (tid < 128) {
        const int col = tid - 64;
        float s = 0.f;
#pragma unroll
        for (int k = 0; k < 32; k++) { const float v = ajT[k][col]; s += v * v; }
        nJ[col] = s;
    }
    __syncthreads();

    const int ti = tid >> 4, tj = tid & 15;
    float acc[4][4] = {};
#pragma unroll
    for (int k4 = 0; k4 < 8; k4++) {
        float4 a4[4], b4[4];
#pragma unroll
        for (int r = 0; r < 4; r++) a4[r] = *(const float4*)&ai[ti * 4 + r][k4 * 4];
#pragma unroll
        for (int kk = 0; kk < 4; kk++) b4[kk] = *(const float4*)&ajT[k4 * 4 + kk][tj * 4];
#pragma unroll
        for (int r = 0; r < 4; r++) {
            acc[r][0] += a4[r].x * b4[0].x + a4[r].y * b4[1].x + a4[r].z * b4[2].x + a4[r].w * b4[3].x;
            acc[r][1] += a4[r].x * b4[0].y + a4[r].y * b4[1].y + a4[r].z * b4[2].y + a4[r].w * b4[3].y;
            acc[r][2] += a4[r].x * b4[0].z + a4[r].y * b4[1].z + a4[r].z * b4[2].z + a4[r].w * b4[3].z;
            acc[r][3] += a4[r].x * b4[0].w + a4[r].y * b4[1].w + a4[r].z * b4[2].w + a4[r].w * b4[3].w;
        }
    }
#pragma unroll
    for (int r = 0; r < 4; r++) {
        const int i = i0 + ti * 4 + r;
        const float ni = nI[ti * 4 + r];
        float e[4];
#pragma unroll
        for (int c = 0; c < 4; c++) {
            const float dist = ni + nJ[tj * 4 + c] - 2.f * acc[r][c];
            e[c] = __expf(__expf(-gamma * dist));
        }
        rm[ti * 4 + r][tj] = e[0] + e[1] + e[2] + e[3];
        const float4 dr = *(const float4*)&drop[(size_t)i * N_NODES + j0 + tj * 4];
        *(float4*)(&Ehat[(size_t)i * N_NODES + j0 + tj * 4]) =
            make_float4(e[0] * dr.x, e[1] * dr.y, e[2] * dr.z, e[3] * dr.w);
    }
    __syncthreads();
    if (tid < 64) {
        float s = 0.f;
#pragma unroll
        for (int t = 0; t < 16; t++) s += rm[tid][t];
        Psum[(size_t)blockIdx.x * N_NODES + i0 + tid] = s;
    }
}

// ---------------------------------------------------------------------------
// k_inv: 64 blocks x 32 rows. inv[i]; U=p*adj; Up=inv*U; qpart.
// ---------------------------------------------------------------------------
__global__ __launch_bounds__(256) void k_inv(
    const float* __restrict__ Psum, const float* __restrict__ adj,
    const float* __restrict__ p,
    float* __restrict__ inv, float* __restrict__ U, float* __restrict__ Up,
    float* __restrict__ qpart)
{
    __shared__ float red[256];
    __shared__ float invL[32];
    __shared__ float uL[32][33];
    const int tid = threadIdx.x;
    const int base = blockIdx.x * 32;
    const int i = tid & 31;
    const int g = tid >> 5;   // 0..7

    float s = 0.f;
#pragma unroll
    for (int t = 0; t < 4; t++)
        s += Psum[(size_t)(g + t * 8) * N_NODES + base + i];
    red[tid] = s;
    __syncthreads();
    if (g == 0) {
        float t = 0.f;
#pragma unroll
        for (int gg = 0; gg < 8; gg++) t += red[gg * 32 + i];
        const float iv = 1.0f / t;
        inv[base + i] = iv;
        invL[i] = iv;
    }
    __syncthreads();

#pragma unroll
    for (int r = 0; r < 4; r++) {
        const int idx = r * 256 + tid;       // 0..1023
        const int row = idx >> 5;
        const float u = p[base + row] * adj[(size_t)base * EMBED + idx];
        uL[row][idx & 31] = u;
        U[(size_t)base * EMBED + idx]  = u;
        Up[(size_t)base * EMBED + idx] = invL[row] * u;
    }
    __syncthreads();
    float qs = 0.f;
#pragma unroll
    for (int r = 0; r < 4; r++) qs += uL[g * 4 + r][i];
    red[tid] = qs;
    __syncthreads();
    if (g == 0) {
        float t = 0.f;
#pragma unroll
        for (int gg = 0; gg < 8; gg++) t += red[gg * 32 + i];
        qpart[blockIdx.x * EMBED + i] = t;
    }
}

// ---------------------------------------------------------------------------
// k_v: Vp[chunk][n][d] partial of V[n,d] = sum_m Ehat[m,n] * Vin[m,d]
// grid (16 n-tiles x 128, 32 m-chunks x 64).  4-deep MLP on Ehat loads.
// ---------------------------------------------------------------------------
__global__ __launch_bounds__(256) void k_v(
    const float* __restrict__ Ehat, const float* __restrict__ Vin,
    float* __restrict__ Vp)
{
    __shared__ float Us[64 * 32];
    const int tid = threadIdx.x;
    const int n  = blockIdx.x * 128 + (tid & 127);
    const int dh = (tid >> 7) * 16;          // 0 or 16
    const int m0 = blockIdx.y * 64;

#pragma unroll
    for (int r = 0; r < 8; r++) {
        const int idx = r * 256 + tid;       // 0..2047
        Us[idx] = Vin[(size_t)m0 * EMBED + idx];
    }
    __syncthreads();

    const float* Ep = &Ehat[(size_t)m0 * N_NODES + n];
    float4 a0 = {}, a1 = {}, a2 = {}, a3 = {};
    for (int mm = 0; mm < 64; mm += 4) {
        const float e0 = Ep[(size_t)(mm + 0) * N_NODES];
        const float e1 = Ep[(size_t)(mm + 1) * N_NODES];
        const float e2 = Ep[(size_t)(mm + 2) * N_NODES];
        const float e3 = Ep[(size_t)(mm + 3) * N_NODES];
#pragma unroll
        for (int j = 0; j < 4; j++) {
            const float e = (j == 0) ? e0 : (j == 1) ? e1 : (j == 2) ? e2 : e3;
            const float4* u4 = (const float4*)&Us[(mm + j) * 32 + dh];
            const float4 u0 = u4[0], u1 = u4[1], u2 = u4[2], u3 = u4[3];
            a0.x += e * u0.x; a0.y += e * u0.y; a0.z += e * u0.z; a0.w += e * u0.w;
            a1.x += e * u1.x; a1.y += e * u1.y; a1.z += e * u1.z; a1.w += e * u1.w;
            a2.x += e * u2.x; a2.y += e * u2.y; a2.z += e * u2.z; a2.w += e * u2.w;
            a3.x += e * u3.x; a3.y += e * u3.y; a3.z += e * u3.z; a3.w += e * u3.w;
        }
    }
    float4* out = (float4*)(Vp + (size_t)blockIdx.y * (N_NODES * EMBED)
                               + (size_t)n * EMBED + dh);
    out[0] = a0; out[1] = a1; out[2] = a2; out[3] = a3;
}

// ---------------------------------------------------------------------------
// k_vred: V[idx] = sum over 32 chunks; optionally Vprime = inv[row]*V.
// ---------------------------------------------------------------------------
__global__ __launch_bounds__(256) void k_vred(
    const float* __restrict__ Vp, const float* __restrict__ inv,
    float* __restrict__ V, float* __restrict__ Vprime, int writePrime)
{
    const int idx = blockIdx.x * 256 + threadIdx.x;   // 0..65535
    float s = 0.f;
#pragma unroll
    for (int c = 0; c < 32; c++) s += Vp[(size_t)c * (N_NODES * EMBED) + idx];
    V[idx] = s;
    if (writePrime) Vprime[idx] = inv[idx >> 5] * s;
}

// ---------------------------------------------------------------------------
// k_M: partials of M_k[d,c] = sum_n Vk[n,d] * X'[c,n], all k fused.
// grid (16 c-tiles x 32, 32 n-chunks x 64), 256 threads.
// ---------------------------------------------------------------------------
__global__ __launch_bounds__(256) void k_M(
    const float* __restrict__ XT, const float* __restrict__ V0,
    const float* __restrict__ V1, const float* __restrict__ V2,
    float* __restrict__ Mp)
{
    __shared__ float xs[32][65];
    __shared__ float vs[3][64 * 32];
    const int tid = threadIdx.x;
    const int c0 = blockIdx.x * 32;
    const int n0 = blockIdx.y * 64;
    const int d  = tid >> 3;
    const int cg = (tid & 7) * 4;

#pragma unroll
    for (int r = 0; r < 8; r++) {
        const int idx = r * 256 + tid;        // 0..2047
        xs[idx >> 6][idx & 63] = XT[(size_t)(c0 + (idx >> 6)) * N_NODES + n0 + (idx & 63)];
        vs[0][idx] = V0[(size_t)n0 * EMBED + idx];
        vs[1][idx] = V1[(size_t)n0 * EMBED + idx];
        vs[2][idx] = V2[(size_t)n0 * EMBED + idx];
    }
    __syncthreads();

    float acc[3][4] = {};
#pragma unroll 4
    for (int nn = 0; nn < 64; nn++) {
        const float v0 = vs[0][nn * 32 + d];
        const float v1 = vs[1][nn * 32 + d];
        const float v2 = vs[2][nn * 32 + d];
#pragma unroll
        for (int cc = 0; cc < 4; cc++) {
            const float xv = xs[cg + cc][nn];
            acc[0][cc] += xv * v0;
            acc[1][cc] += xv * v1;
            acc[2][cc] += xv * v2;
        }
    }
#pragma unroll
    for (int k = 0; k < 3; k++) {
        float* dst = Mp + ((size_t)(blockIdx.y * 3 + k) * EMBED + d) * NCOL + c0 + cg;
        *(float4*)dst = make_float4(acc[k][0], acc[k][1], acc[k][2], acc[k][3]);
    }
}

// ---------------------------------------------------------------------------
// k_Mred: coalesced reduction of Mp chunks -> M (49152 floats).
// 192 blocks x 256 threads; 32 independent strided loads per thread.
// ---------------------------------------------------------------------------
__global__ __launch_bounds__(256) void k_Mred(
    const float* __restrict__ Mp, float* __restrict__ M)
{
    const int idx = blockIdx.x * 256 + threadIdx.x;   // 0..49151
    float s = 0.f;
#pragma unroll
    for (int c = 0; c < 32; c++)
        s += Mp[(size_t)c * (CHEB_K * EMBED * NCOL) + idx];
    M[idx] = s;
}

// ---------------------------------------------------------------------------
// k_final: 128 blocks = (d 0..31) x (o-group 0..3). Reads pre-reduced M[d]
// (6KB) + W slice from L2; atomicAdd d-partials into zeroed out.
// ---------------------------------------------------------------------------
__global__ __launch_bounds__(256) void k_final(
    const float* __restrict__ M, const float* __restrict__ W,
    const float* __restrict__ bp, const float* __restrict__ qpart,
    const float* __restrict__ pb, float* __restrict__ out)
{
    const int d  = blockIdx.x >> 2;
    const int og = (blockIdx.x & 3) * 8;
    const int tid = threadIdx.x;
    __shared__ float mL[3 * 512];
    __shared__ float qL[32];

#pragma unroll
    for (int r = 0; r < 6; r++) {
        const int e = r * 256 + tid;             // 0..1535
        mL[e] = M[(size_t)((e >> 9) * EMBED + d) * NCOL + (e & 511)];
    }
    if (d == 0 && tid < 32) {
        float s = 0.f;
#pragma unroll
        for (int mc = 0; mc < 64; mc++) s += qpart[mc * EMBED + tid];
        qL[tid] = s;
    }
    __syncthreads();

    if (tid < 128) {
        const int b = tid >> 3;
        const int o = og + (tid & 7);
        float acc = 0.f;
#pragma unroll
        for (int i = 0; i < 32; i++) {
            const float m0 = mL[b * 32 + i];
            const float m1 = mL[512 + b * 32 + i];
            const float m2 = mL[1024 + b * 32 + i];
            const float w0 = W[((size_t)(d * 3 + 0) * 32 + i) * 32 + o];
            const float w1 = W[((size_t)(d * 3 + 1) * 32 + i) * 32 + o];
            const float w2 = W[((size_t)(d * 3 + 2) * 32 + i) * 32 + o];
            acc += m0 * (w0 - w2) + m1 * w1 + 2.f * m2 * w2;
        }
        if (d == 0) {
            float bias = pb[0];
#pragma unroll
            for (int dd = 0; dd < 32; dd++) bias += qL[dd] * bp[dd * OUTC + o];
            acc += bias;
        }
        atomicAdd(&out[b * OUTC + o], acc);
    }
}

// ---------------------------------------------------------------------------
extern "C" void kernel_launch(void* const* d_in, const int* in_sizes, int n_in,
                              void* d_out, int out_size, void* d_ws, size_t ws_size,
                              hipStream_t stream)
{
    const float* x     = (const float*)d_in[0];
    const float* adj   = (const float*)d_in[1];
    const float* gamma = (const float*)d_in[2];
    const float* Wp    = (const float*)d_in[3];
    const float* bp    = (const float*)d_in[4];
    const float* pw    = (const float*)d_in[5];
    const float* pb    = (const float*)d_in[6];
    const float* drop  = (const float*)d_in[7];
    float* out = (float*)d_out;

    float* ws = (float*)d_ws;
    float* Ehat  = ws;                                        // 16 MB
    float* Vp    = Ehat + (size_t)N_NODES * N_NODES;          // 8 MB (32 chunks)
    float* Mp    = Vp;                                        // alias (6 MB, after Vp done)
    float* Psum  = Vp   + (size_t)32 * N_NODES * EMBED;       // 256 KB
    float* inv   = Psum + (size_t)32 * N_NODES;               // 8 KB
    float* U     = inv  + N_NODES;                            // 256 KB
    float* Up    = U    + (size_t)N_NODES * EMBED;            // 256 KB
    float* V1    = Up   + (size_t)N_NODES * EMBED;            // 256 KB
    float* V1p   = V1   + (size_t)N_NODES * EMBED;            // 256 KB
    float* V2    = V1p  + (size_t)N_NODES * EMBED;            // 256 KB
    float* M     = V2   + (size_t)N_NODES * EMBED;            // 192 KB
    float* qpart = M    + (size_t)CHEB_K * EMBED * NCOL;      // 8 KB

    hipMemsetAsync(out, 0, (size_t)B_BATCH * OUTC * sizeof(float), stream);

    k_gram<<<dim3(32, 32), 256, 0, stream>>>(adj, gamma, drop, Ehat, Psum);
    k_inv<<<64, 256, 0, stream>>>(Psum, adj, pw, inv, U, Up, qpart);

    dim3 gv(16, 32);
    k_v<<<gv, 256, 0, stream>>>(Ehat, Up, Vp);
    k_vred<<<256, 256, 0, stream>>>(Vp, inv, V1, V1p, 1);
    k_v<<<gv, 256, 0, stream>>>(Ehat, V1p, Vp);
    k_vred<<<256, 256, 0, stream>>>(Vp, inv, V2, V2, 0);

    k_M<<<dim3(16, 32), 256, 0, stream>>>(x, U, V1, V2, Mp);
    k_Mred<<<192, 256, 0, stream>>>(Mp, M);
    k_final<<<128, 256, 0, stream>>>(M, Wp, bp, qpart, pb, out);
}